// Round 6
// baseline (375.288 us; speedup 1.0000x reference)
//
#include <hip/hip_runtime.h>

// KacLayer: out[512][4096] = x @ W^T + b  +  Kac2( vec * Kac1( x ) )
//
//  ksched: per 8192-step window: (1) dependency-round election (round-stamped
//          atomicMin keys; round == chain depth, program order preserved on
//          shared columns); (2) greedy chunk-packing: chunk(s) = earliest
//          chunk >= cchunk[col]+3 with capacity 128 (atomic spill-forward).
//          => any column-sharing steps are >=3 chunks apart => any 3
//          consecutive chunks column-disjoint; no inter-round pads.
//          2 trailing pad chunks per window separate windows. Bit-exact.
//  kgemm : bf16-MFMA GEMM (R3 version), out = x@W^T + b.
//  kwalk : 1 wave / 2 rows (float2-interleaved LDS). 3-stage pipeline:
//          records loaded 4 chunks ahead, decoded+gathered 2 ahead,
//          rotated+scattered at stage 0. In-order DS pipe + the >=3-chunk
//          separation invariant make gather-before-scatter safe.

#define DIM    4096
#define ROWS   512
#define NSTEPS 49152
#define WSTEPS 8192
#define NW2    (NSTEPS / WSTEPS)   // 6 windows per walk
#define NSLOT  (2 * NW2)           // 12 slots
#define MAXR   64
#define MAXCH  147                 // real chunks per slot cap
#define SLOT   19200               // 150*128 records per slot
#define CHUNK  128
#define GD     3                   // min chunk separation for dependent steps
#define PADI   4096
#define PADJ   4097
#define KT     1024                // ksched threads
#define SPT    (WSTEPS / KT)       // 8 steps per thread

typedef short  short8 __attribute__((ext_vector_type(8)));
typedef __bf16 bf16x8 __attribute__((ext_vector_type(8)));
typedef float  f32x4  __attribute__((ext_vector_type(4)));

__device__ inline short f2bf(float f) {
    unsigned u = __builtin_bit_cast(unsigned, f);
    u += 0x7FFFu + ((u >> 16) & 1u);
    return (short)(u >> 16);
}
__device__ inline short8 pack8(float4 a, float4 b) {
    short8 r;
    r[0] = f2bf(a.x); r[1] = f2bf(a.y); r[2] = f2bf(a.z); r[3] = f2bf(a.w);
    r[4] = f2bf(b.x); r[5] = f2bf(b.y); r[6] = f2bf(b.z); r[7] = f2bf(b.w);
    return r;
}
__device__ inline float bitf(unsigned u) { return __builtin_bit_cast(float, u); }

// ---------------------------------------------------------------------------
// 1) schedule kernel: one block per 8192-step window
// ---------------------------------------------------------------------------
__global__ __launch_bounds__(KT) void ksched(
    const int* __restrict__ i1, const int* __restrict__ j1,
    const float* __restrict__ c1, const float* __restrict__ s1,
    const int* __restrict__ i2, const int* __restrict__ j2,
    const float* __restrict__ c2, const float* __restrict__ s2,
    uint4* __restrict__ recs, int* __restrict__ cnts) {

    __shared__ unsigned tbl[DIM];          // election keys
    __shared__ int      cchunk[DIM];       // last chunk using column
    __shared__ unsigned short inv[SLOT];   // position -> step
    __shared__ int fill[MAXCH];
    __shared__ int rmaxsh, maxcsh, done;

    const int b    = blockIdx.x;            // 0..11
    const int walk = b / NW2;
    const int w    = b % NW2;
    const int t    = threadIdx.x;
    const int gb   = w * WSTEPS;

    const int*   I = walk ? i2 : i1;
    const int*   J = walk ? j2 : j1;
    const float* C = walk ? c2 : c1;
    const float* S = walk ? s2 : s1;

    unsigned short li[SPT], lj[SPT];
    signed char    myr[SPT];
#pragma unroll
    for (int q = 0; q < SPT; ++q) {
        const int s = q * KT + t;
        li[q] = (unsigned short)I[gb + s];
        lj[q] = (unsigned short)J[gb + s];
        myr[q] = -1;
    }
    for (int k = t; k < DIM; k += KT) tbl[k] = 0xFFFFFFFFu;
    if (t < MAXCH) fill[t] = 0;
    if (t == 0) { rmaxsh = 0; maxcsh = 0; done = 0; }
    __syncthreads();

    // ---- election: key = ((MAXR-1-rr)<<13)|step; winner = min on BOTH cols
    unsigned pmask = (1u << SPT) - 1u;
    for (int rr = 0; rr < MAXR; ++rr) {
        const unsigned rk = (unsigned)(MAXR - 1 - rr) << 13;
#pragma unroll
        for (int q = 0; q < SPT; ++q)
            if (pmask & (1u << q)) {
                const unsigned key = rk | (unsigned)(q * KT + t);
                atomicMin(&tbl[li[q]], key);
                atomicMin(&tbl[lj[q]], key);
            }
        __syncthreads();
        int wins = 0;
#pragma unroll
        for (int q = 0; q < SPT; ++q)
            if (pmask & (1u << q)) {
                const unsigned key = rk | (unsigned)(q * KT + t);
                if (tbl[li[q]] == key && tbl[lj[q]] == key) {
                    myr[q] = (signed char)rr; pmask &= ~(1u << q); ++wins;
                }
            }
        if (wins) atomicAdd(&done, wins);
        __syncthreads();
        if (done == WSTEPS) break;
    }
    {
        int lmax = 0;
#pragma unroll
        for (int q = 0; q < SPT; ++q) {
            if (myr[q] < 0) myr[q] = MAXR - 1;   // statistically unreachable
            lmax = (myr[q] > lmax) ? myr[q] : lmax;
        }
        atomicMax(&rmaxsh, lmax);
    }
    for (int k = t; k < DIM; k += KT) cchunk[k] = -GD;
    __syncthreads();

    // ---- greedy chunk assignment, rounds in order --------------------------
    const int rmax = rmaxsh;
    unsigned short pplace[SPT];
#pragma unroll
    for (int q = 0; q < SPT; ++q) pplace[q] = 0xFFFFu;
    for (int r = 0; r <= rmax; ++r) {
#pragma unroll
        for (int q = 0; q < SPT; ++q)
            if ((int)myr[q] == r) {
                const int a = cchunk[li[q]], c = cchunk[lj[q]];
                int mc = ((a > c) ? a : c) + GD;
                if (mc < 0) mc = 0;
                int pos;
                for (;;) {
                    pos = atomicAdd(&fill[mc], 1);
                    if (pos < CHUNK || mc >= MAXCH - 1) break;
                    ++mc;
                }
                const int p = mc * CHUNK + pos;
                if (p < SLOT) pplace[q] = (unsigned short)p;
                cchunk[li[q]] = mc; cchunk[lj[q]] = mc;
                atomicMax(&maxcsh, mc);
            }
        __syncthreads();
    }

    // ---- emission: inv table, then coalesced position-ordered records ------
    const int stotal0 = (maxcsh + 1 + 2) * CHUNK;      // +2 trailing pad chunks
    const int stotal  = (stotal0 > SLOT) ? SLOT : stotal0;
    if (t == 0) cnts[b] = stotal;
    for (int k = t; k < stotal; k += KT) inv[k] = 0xFFFFu;
    __syncthreads();
#pragma unroll
    for (int q = 0; q < SPT; ++q)
        if (pplace[q] != 0xFFFFu) inv[pplace[q]] = (unsigned short)(q * KT + t);
    __syncthreads();

    uint4* slotp = recs + (size_t)b * SLOT;
    for (int k = t; k < stotal; k += KT) {
        const unsigned s = inv[k];
        uint4 r = { (unsigned)PADI | ((unsigned)PADJ << 16), 0x3F800000u, 0u, 0u };
        if (s != 0xFFFFu) {
            const int g = gb + (int)s;
            r.x = (unsigned)I[g] | ((unsigned)J[g] << 16);
            r.y = __builtin_bit_cast(unsigned, C[g]);
            r.z = __builtin_bit_cast(unsigned, S[g]);
        }
        slotp[k] = r;
    }
}

// ---------------------------------------------------------------------------
// 2) bf16 MFMA GEMM: out = x @ W^T + b      (BM=64, BN=128, BK=64, 256 thr)
// ---------------------------------------------------------------------------
#define BM  64
#define BN  128
#define BK  64
#define LDT 72

__global__ __launch_bounds__(256) void kgemm(const float* __restrict__ X, const float* __restrict__ W,
                                             const float* __restrict__ bias, float* __restrict__ out) {
    __shared__ short As[BM * LDT];
    __shared__ short Bs[BN * LDT];
    const int tid  = threadIdx.x;
    const int bn   = (blockIdx.x & 31) * BN;
    const int bm   = (blockIdx.x >> 5) * BM;
    const int lane = tid & 63;
    const int wv   = tid >> 6;
    const int wr   = (wv >> 1) * 32;
    const int wc   = (wv & 1) * 64;
    const int fr   = lane & 15;
    const int ke   = (lane >> 4) * 8;

    f32x4 acc[2][4];
#pragma unroll
    for (int m = 0; m < 2; ++m)
#pragma unroll
        for (int n = 0; n < 4; ++n) acc[m][n] = (f32x4){0.f, 0.f, 0.f, 0.f};

    const int tr = tid >> 2;
    const int tc = (tid & 3) << 4;

    for (int kt = 0; kt < DIM / BK; ++kt) {
        const int k0 = kt * BK;
        float4 ra[4], rb[2][4];
        {
            const float4* ga = (const float4*)(X + (size_t)(bm + tr) * DIM + k0 + tc);
#pragma unroll
            for (int q = 0; q < 4; ++q) ra[q] = ga[q];
#pragma unroll
            for (int h = 0; h < 2; ++h) {
                const float4* gb = (const float4*)(W + (size_t)(bn + h * 64 + tr) * DIM + k0 + tc);
#pragma unroll
                for (int q = 0; q < 4; ++q) rb[h][q] = gb[q];
            }
        }
        __syncthreads();
        *(short8*)&As[tr * LDT + tc]     = pack8(ra[0], ra[1]);
        *(short8*)&As[tr * LDT + tc + 8] = pack8(ra[2], ra[3]);
#pragma unroll
        for (int h = 0; h < 2; ++h) {
            *(short8*)&Bs[(h * 64 + tr) * LDT + tc]     = pack8(rb[h][0], rb[h][1]);
            *(short8*)&Bs[(h * 64 + tr) * LDT + tc + 8] = pack8(rb[h][2], rb[h][3]);
        }
        __syncthreads();
#pragma unroll
        for (int kk = 0; kk < BK; kk += 32) {
            short8 af[2], bf[4];
#pragma unroll
            for (int m = 0; m < 2; ++m)
                af[m] = *(const short8*)&As[(wr + m * 16 + fr) * LDT + kk + ke];
#pragma unroll
            for (int n = 0; n < 4; ++n)
                bf[n] = *(const short8*)&Bs[(wc + n * 16 + fr) * LDT + kk + ke];
#pragma unroll
            for (int m = 0; m < 2; ++m)
#pragma unroll
                for (int n = 0; n < 4; ++n)
                    acc[m][n] = __builtin_amdgcn_mfma_f32_16x16x32_bf16(
                        __builtin_bit_cast(bf16x8, af[m]),
                        __builtin_bit_cast(bf16x8, bf[n]),
                        acc[m][n], 0, 0, 0);
        }
    }
#pragma unroll
    for (int n = 0; n < 4; ++n) {
        const int col = bn + wc + n * 16 + fr;
        const float bv = bias[col];
#pragma unroll
        for (int m = 0; m < 2; ++m) {
            const int rbase = bm + wr + m * 16 + (lane >> 4) * 4;
#pragma unroll
            for (int r = 0; r < 4; ++r)
                out[(size_t)(rbase + r) * DIM + col] = acc[m][n][r] + bv;
        }
    }
}

// ---------------------------------------------------------------------------
// 3) walk kernel: 1 wave / 2 rows, 3-stage pipeline (load+4 / gather+2 / do)
// ---------------------------------------------------------------------------
__global__ __launch_bounds__(64) void kwalk(const float* __restrict__ X, const float* __restrict__ vec,
                                            const uint4* __restrict__ recs, const int* __restrict__ cnts,
                                            float* __restrict__ out) {
    __shared__ float2 rw[DIM + 2];          // rw[c] = {rowA[c], rowB[c]}
    const int pr   = blockIdx.x;
    const int lane = threadIdx.x;
    const int rA   = pr * 2, rB = pr * 2 + 1;

    {
        const float4* xa = (const float4*)(X + (size_t)rA * DIM);
        const float4* xb = (const float4*)(X + (size_t)rB * DIM);
        for (int c4 = lane; c4 < DIM / 4; c4 += 64) {
            const float4 a = xa[c4], b = xb[c4];
            rw[c4 * 4 + 0] = make_float2(a.x, b.x);
            rw[c4 * 4 + 1] = make_float2(a.y, b.y);
            rw[c4 * 4 + 2] = make_float2(a.z, b.z);
            rw[c4 * 4 + 3] = make_float2(a.w, b.w);
        }
        if (lane < 2) rw[DIM + lane] = make_float2(0.f, 0.f);
    }

    const int cnreg = cnts[lane < NSLOT ? lane : 0];

    for (int slot = 0; slot < NSLOT; ++slot) {
        if (slot == NW2) {      // between walks: yp = vec * yp
            const float4* v4 = (const float4*)vec;
            for (int c4 = lane; c4 < DIM / 4; c4 += 64) {
                const float4 v = v4[c4];
#pragma unroll
                for (int q = 0; q < 4; ++q) {
                    float2 tv = rw[c4 * 4 + q];
                    const float sc = (q == 0) ? v.x : (q == 1) ? v.y : (q == 2) ? v.z : v.w;
                    tv.x *= sc; tv.y *= sc;
                    rw[c4 * 4 + q] = tv;
                }
            }
        }
        const int nit = __shfl(cnreg, slot) >> 7;     // chunks this slot
        const uint4* base = recs + (size_t)slot * SLOT;

        // ---- prologue: record ring holds chunks k+2,k+3; stages 0,1 filled
        uint4 rd0A = base[2 * 128 + lane], rd0B = base[2 * 128 + 64 + lane];
        uint4 rd1A = base[3 * 128 + lane], rd1B = base[3 * 128 + 64 + lane];
        uint4 c0A  = base[lane],           c0B  = base[64 + lane];
        uint4 c1A  = base[128 + lane],     c1B  = base[192 + lane];

        int   i0a = c0A.x & 0xFFFF, j0a = (int)(c0A.x >> 16);
        int   i0b = c0B.x & 0xFFFF, j0b = (int)(c0B.x >> 16);
        float cc0a = bitf(c0A.y), ss0a = bitf(c0A.z);
        float cc0b = bitf(c0B.y), ss0b = bitf(c0B.z);
        float2 g0ai = rw[i0a], g0aj = rw[j0a], g0bi = rw[i0b], g0bj = rw[j0b];

        int   i1a = c1A.x & 0xFFFF, j1a = (int)(c1A.x >> 16);
        int   i1b = c1B.x & 0xFFFF, j1b = (int)(c1B.x >> 16);
        float cc1a = bitf(c1A.y), ss1a = bitf(c1A.z);
        float cc1b = bitf(c1B.y), ss1b = bitf(c1B.z);
        float2 g1ai = rw[i1a], g1aj = rw[j1a], g1bi = rw[i1b], g1bj = rw[j1b];

#pragma unroll 4
        for (int k = 0; k < nit; ++k) {
            // stage L: load records for chunk k+4 (clamped -> trailing pads)
            const int kc = (k + 4 < nit) ? (k + 4) : (nit - 1);
            const uint4 mA = base[(size_t)kc * 128 + lane];
            const uint4 mB = base[(size_t)kc * 128 + 64 + lane];

            // stage G: decode + gather chunk k+2 (safe: any 3 consecutive
            // chunks column-disjoint by the >=3-separation invariant)
            const int   i2a = rd0A.x & 0xFFFF, j2a = (int)(rd0A.x >> 16);
            const int   i2b = rd0B.x & 0xFFFF, j2b = (int)(rd0B.x >> 16);
            const float cc2a = bitf(rd0A.y), ss2a = bitf(rd0A.z);
            const float cc2b = bitf(rd0B.y), ss2b = bitf(rd0B.z);
            const float2 g2ai = rw[i2a], g2aj = rw[j2a];
            const float2 g2bi = rw[i2b], g2bj = rw[j2b];

            // stage C: rotate + scatter chunk k
            float2 wia, wja, wib, wjb;
            wia.x = fmaf(cc0a, g0ai.x,  ss0a * g0aj.x);
            wia.y = fmaf(cc0a, g0ai.y,  ss0a * g0aj.y);
            wja.x = fmaf(cc0a, g0aj.x, -ss0a * g0ai.x);
            wja.y = fmaf(cc0a, g0aj.y, -ss0a * g0ai.y);
            wib.x = fmaf(cc0b, g0bi.x,  ss0b * g0bj.x);
            wib.y = fmaf(cc0b, g0bi.y,  ss0b * g0bj.y);
            wjb.x = fmaf(cc0b, g0bj.x, -ss0b * g0bi.x);
            wjb.y = fmaf(cc0b, g0bj.y, -ss0b * g0bi.y);
            rw[i0a] = wia; rw[j0a] = wja; rw[i0b] = wib; rw[j0b] = wjb;

            // rotate pipeline
            i0a = i1a; j0a = j1a; cc0a = cc1a; ss0a = ss1a; g0ai = g1ai; g0aj = g1aj;
            i0b = i1b; j0b = j1b; cc0b = cc1b; ss0b = ss1b; g0bi = g1bi; g0bj = g1bj;
            i1a = i2a; j1a = j2a; cc1a = cc2a; ss1a = ss2a; g1ai = g2ai; g1aj = g2aj;
            i1b = i2b; j1b = j2b; cc1b = cc2b; ss1b = ss2b; g1bi = g2bi; g1bj = g2bj;
            rd0A = rd1A; rd0B = rd1B; rd1A = mA; rd1B = mB;
        }
    }

    float4* oa = (float4*)(out + (size_t)rA * DIM);
    float4* ob = (float4*)(out + (size_t)rB * DIM);
    for (int c4 = lane; c4 < DIM / 4; c4 += 64) {
        const float2 p0 = rw[c4 * 4 + 0], p1 = rw[c4 * 4 + 1];
        const float2 p2 = rw[c4 * 4 + 2], p3 = rw[c4 * 4 + 3];
        float4 ta = oa[c4], tb = ob[c4];
        ta.x += p0.x; ta.y += p1.x; ta.z += p2.x; ta.w += p3.x;
        tb.x += p0.y; tb.y += p1.y; tb.z += p2.y; tb.w += p3.y;
        oa[c4] = ta; ob[c4] = tb;
    }
}

// ---------------------------------------------------------------------------
extern "C" void kernel_launch(void* const* d_in, const int* in_sizes, int n_in,
                              void* d_out, int out_size, void* d_ws, size_t ws_size,
                              hipStream_t stream) {
    const float* X    = (const float*)d_in[0];
    const float* W    = (const float*)d_in[1];
    const float* bias = (const float*)d_in[2];
    const float* vec  = (const float*)d_in[3];
    const int*   i1   = (const int*)d_in[4];
    const int*   j1   = (const int*)d_in[5];
    const float* c1   = (const float*)d_in[6];
    const float* s1   = (const float*)d_in[7];
    const int*   i2   = (const int*)d_in[8];
    const int*   j2   = (const int*)d_in[9];
    const float* c2   = (const float*)d_in[10];
    const float* s2   = (const float*)d_in[11];
    float* out = (float*)d_out;

    uint4* recs = (uint4*)d_ws;                        // 12*19200*16B = 3.52 MiB
    int*   cnts = (int*)((char*)d_ws + (size_t)NSLOT * SLOT * 16);

    hipLaunchKernelGGL(ksched, dim3(NSLOT), dim3(KT), 0, stream,
                       i1, j1, c1, s1, i2, j2, c2, s2, recs, cnts);
    hipLaunchKernelGGL(kgemm,  dim3(256), dim3(256), 0, stream, X, W, bias, out);
    hipLaunchKernelGGL(kwalk,  dim3(ROWS / 2), dim3(64), 0, stream, X, vec, recs, cnts, out);
}

// Round 7
// 367.994 us; speedup vs baseline: 1.0198x; 1.0198x over previous
//
#include <hip/hip_runtime.h>

// KacLayer: out[512][4096] = x @ W^T + b  +  Kac2( vec * Kac1( x ) )
//
//  ksched: per 8192-step window: (1) dependency-round election (round-stamped
//          atomicMin keys; program order preserved on shared columns);
//          (2) per-round FIFO chunk placement: step's min chunk =
//          max(cchunk[cols])+3; capacity-128 packing computed by a (min,+)
//          function-composition wave scan (no quadratic atomic spin).
//          => column-sharing steps >=3 chunks apart => any 3 consecutive
//          chunks column-disjoint. 2 trailing pad chunks/window. Bit-exact.
//  kgemm : bf16-MFMA GEMM, BM=128 BN=256, K-split=4 into out + 3 partial
//          buffers (deterministic, no atomics). Fallback: old 64x128 kernel.
//  kwalk : 1 wave / 2 rows (float2-interleaved LDS), 3-stage pipeline
//          (records loaded +4, gathered +2, scattered at 0); epilogue adds
//          split-K partials + walked rows into out.

#define DIM    4096
#define ROWS   512
#define NSTEPS 49152
#define WSTEPS 8192
#define NW2    (NSTEPS / WSTEPS)   // 6 windows per walk
#define NSLOT  (2 * NW2)           // 12 slots
#define MAXCH  254
#define MAXCHP 256
#define CHUNK  128
#define SLOT   ((MAXCH + 2) * CHUNK)   // 32768 records per slot
#define MAXR   64
#define GD     3                   // min chunk separation for dependent steps
#define PADI   4096
#define PADJ   4097
#define KT     1024                // ksched threads
#define SPT    (WSTEPS / KT)       // 8 steps per thread

typedef short  short8 __attribute__((ext_vector_type(8)));
typedef __bf16 bf16x8 __attribute__((ext_vector_type(8)));
typedef float  f32x4  __attribute__((ext_vector_type(4)));

__device__ inline short f2bf(float f) {
    unsigned u = __builtin_bit_cast(unsigned, f);
    u += 0x7FFFu + ((u >> 16) & 1u);
    return (short)(u >> 16);
}
__device__ inline short8 pack8(float4 a, float4 b) {
    short8 r;
    r[0] = f2bf(a.x); r[1] = f2bf(a.y); r[2] = f2bf(a.z); r[3] = f2bf(a.w);
    r[4] = f2bf(b.x); r[5] = f2bf(b.y); r[6] = f2bf(b.z); r[7] = f2bf(b.w);
    return r;
}
__device__ inline float bitf(unsigned u) { return __builtin_bit_cast(float, u); }

// ---------------------------------------------------------------------------
// 1) schedule kernel: one block per 8192-step window
// ---------------------------------------------------------------------------
__global__ __launch_bounds__(KT) void ksched(
    const int* __restrict__ i1, const int* __restrict__ j1,
    const float* __restrict__ c1, const float* __restrict__ s1,
    const int* __restrict__ i2, const int* __restrict__ j2,
    const float* __restrict__ c2, const float* __restrict__ s2,
    uint4* __restrict__ recs, int* __restrict__ cnts) {

    __shared__ unsigned tbl[DIM];              // election keys (16 KB)
    __shared__ short    cchunk[DIM];           // last chunk per column (8 KB)
    __shared__ unsigned short inv[SLOT];       // position -> step (64 KB)
    __shared__ int want[MAXCHP], gsum[MAXCHP], fillc[MAXCHP], fillb[MAXCHP], cumpl[MAXCHP];
    __shared__ int rmaxsh, maxcsh, done;

    const int b    = blockIdx.x;               // 0..11
    const int walk = b / NW2;
    const int w    = b % NW2;
    const int t    = threadIdx.x;
    const int gb   = w * WSTEPS;

    const int*   I = walk ? i2 : i1;
    const int*   J = walk ? j2 : j1;
    const float* C = walk ? c2 : c1;
    const float* S = walk ? s2 : s1;

    unsigned short li[SPT], lj[SPT];
    signed char    myr[SPT];
#pragma unroll
    for (int q = 0; q < SPT; ++q) {
        const int s = q * KT + t;
        li[q] = (unsigned short)I[gb + s];
        lj[q] = (unsigned short)J[gb + s];
        myr[q] = -1;
    }
    for (int k = t; k < DIM; k += KT) tbl[k] = 0xFFFFFFFFu;
    if (t < MAXCHP) { want[t] = 0; fillc[t] = 0; }
    if (t == 0) { rmaxsh = 0; maxcsh = 0; done = 0; }
    __syncthreads();

    // ---- election: key = ((MAXR-1-rr)<<13)|step; winner = min on BOTH cols
    unsigned pmask = (1u << SPT) - 1u;
    for (int rr = 0; rr < MAXR; ++rr) {
        const unsigned rk = (unsigned)(MAXR - 1 - rr) << 13;
#pragma unroll
        for (int q = 0; q < SPT; ++q)
            if (pmask & (1u << q)) {
                const unsigned key = rk | (unsigned)(q * KT + t);
                atomicMin(&tbl[li[q]], key);
                atomicMin(&tbl[lj[q]], key);
            }
        __syncthreads();
        int wins = 0;
#pragma unroll
        for (int q = 0; q < SPT; ++q)
            if (pmask & (1u << q)) {
                const unsigned key = rk | (unsigned)(q * KT + t);
                if (tbl[li[q]] == key && tbl[lj[q]] == key) {
                    myr[q] = (signed char)rr; pmask &= ~(1u << q); ++wins;
                }
            }
        if (wins) atomicAdd(&done, wins);
        __syncthreads();
        if (done == WSTEPS) break;
    }
    {
        int lmax = 0;
#pragma unroll
        for (int q = 0; q < SPT; ++q) {
            if (myr[q] < 0) myr[q] = MAXR - 1;   // statistically unreachable
            lmax = (myr[q] > lmax) ? myr[q] : lmax;
        }
        atomicMax(&rmaxsh, lmax);
    }
    for (int k = t; k < DIM; k += KT) cchunk[k] = (short)(-GD);
    __syncthreads();

    // ---- per-round FIFO placement with capacity scan ------------------------
    const int rmax = rmaxsh;
    unsigned short pplace[SPT];
    short mcst[SPT], grk[SPT];
#pragma unroll
    for (int q = 0; q < SPT; ++q) pplace[q] = 0xFFFFu;

    for (int r = 0; r <= rmax; ++r) {
        // A: rank within min-chunk group
#pragma unroll
        for (int q = 0; q < SPT; ++q)
            if ((int)myr[q] == r) {
                int a = (int)cchunk[li[q]], c = (int)cchunk[lj[q]];
                int mc = ((a > c) ? a : c) + GD;
                mc = (mc < 0) ? 0 : ((mc > MAXCH - 1) ? MAXCH - 1 : mc);
                mcst[q] = (short)mc;
                grk[q]  = (short)atomicAdd(&want[mc], 1);
            }
        __syncthreads();
        // B: one wave computes gsum (exclusive prefix of want) + capacity
        //    placement via (min,+) composition scan over 256 chunks.
        if (t < 64) {
            const int l = t;
            int wq[4], inc[4], av[4];
            int run = 0;
#pragma unroll
            for (int q = 0; q < 4; ++q) {
                const int ch = 4 * l + q;
                wq[q] = want[ch];
                run += wq[q];
                inc[q] = run;
                av[q] = (ch < MAXCH) ? (CHUNK - fillc[ch]) : 0;
            }
            int tot = run;
            for (int off = 1; off < 64; off <<= 1) {
                int v = __shfl_up(tot, off);
                if (l >= off) tot += v;
            }
            const int basex = tot - run;
#pragma unroll
            for (int q = 0; q < 4; ++q) {
                gsum[4 * l + q] = basex + inc[q] - wq[q];
                inc[q] += basex;
            }
            // lane-local composition of f_ch(x)=min(inc,av+x)
            int Iv = 1 << 29, Av = 0;
#pragma unroll
            for (int q = 0; q < 4; ++q) {
                const int cand = av[q] + Iv;
                Iv = (inc[q] < cand) ? inc[q] : cand;
                Av += av[q];
            }
            // inclusive wave scan, combine cur∘prev
            for (int off = 1; off < 64; off <<= 1) {
                int Ip = __shfl_up(Iv, off), Ap = __shfl_up(Av, off);
                if (l >= off) {
                    const int cand = Av + Ip;
                    Iv = (Iv < cand) ? Iv : cand;
                    Av += Ap;
                }
            }
            const int Ie = __shfl_up(Iv, 1), Ae = __shfl_up(Av, 1);
            int placed = (l == 0) ? 0 : ((Ie < Ae) ? Ie : Ae);
            int lmax = -1;
#pragma unroll
            for (int q = 0; q < 4; ++q) {
                const int ch = 4 * l + q;
                const int cand = av[q] + placed;
                const int pnew = (inc[q] < cand) ? inc[q] : cand;
                const int take = pnew - placed;
                fillb[ch] = (ch < MAXCH) ? fillc[ch] : CHUNK;
                if (ch < MAXCH) fillc[ch] += take;
                cumpl[ch] = pnew;
                if (take > 0) lmax = ch;
                placed = pnew;
            }
            if (lmax >= 0) atomicMax(&maxcsh, lmax);
        }
        __syncthreads();
        // C: each step finds its chunk by binary search on cumpl
#pragma unroll
        for (int q = 0; q < SPT; ++q)
            if ((int)myr[q] == r) {
                const int fifo = gsum[(int)mcst[q]] + (int)grk[q];
                int lo = 0, hi = MAXCHP - 1;
                while (lo < hi) {
                    const int mid = (lo + hi) >> 1;
                    if (cumpl[mid] > fifo) hi = mid; else lo = mid + 1;
                }
                const int ch   = lo;
                const int base = ch ? cumpl[ch - 1] : 0;
                const int p    = ch * CHUNK + fillb[ch] + (fifo - base);
                pplace[q] = (unsigned short)p;
                cchunk[li[q]] = (short)ch;       // no race: round is col-disjoint
                cchunk[lj[q]] = (short)ch;
            }
        if (t < MAXCHP) want[t] = 0;             // reset for next round
        __syncthreads();
    }

    // ---- emission -----------------------------------------------------------
    const int stot0  = (maxcsh + 3) * CHUNK;     // +2 trailing pad chunks
    const int stotal = (stot0 > SLOT) ? SLOT : stot0;
    if (t == 0) cnts[b] = stotal;
    for (int k = t; k < stotal; k += KT) inv[k] = 0xFFFFu;
    __syncthreads();
#pragma unroll
    for (int q = 0; q < SPT; ++q)
        if (pplace[q] != 0xFFFFu) inv[pplace[q]] = (unsigned short)(q * KT + t);
    __syncthreads();

    uint4* slotp = recs + (size_t)b * SLOT;
    for (int k = t; k < stotal; k += KT) {
        const unsigned s = inv[k];
        uint4 r = { (unsigned)PADI | ((unsigned)PADJ << 16), 0x3F800000u, 0u, 0u };
        if (s != 0xFFFFu) {
            const int g = gb + (int)s;
            r.x = (unsigned)I[g] | ((unsigned)J[g] << 16);
            r.y = __builtin_bit_cast(unsigned, C[g]);
            r.z = __builtin_bit_cast(unsigned, S[g]);
        }
        slotp[k] = r;
    }
}

// ---------------------------------------------------------------------------
// 2a) big-tile split-K GEMM: BM=128 BN=256 BK=64, 512 thr, Ksplit=4
// ---------------------------------------------------------------------------
#define BM2 128
#define BN2 256
#define BK2 64
#define LDT 72

__global__ __launch_bounds__(512) void kgemm_big(const float* __restrict__ X, const float* __restrict__ W,
                                                 const float* __restrict__ bias, float* __restrict__ out,
                                                 float* __restrict__ parts) {
    __shared__ short As[BM2 * LDT];
    __shared__ short Bs[BN2 * LDT];
    const int bid  = blockIdx.x;
    const int ks   = bid & 3;                  // K-split index
    const int tile = bid >> 2;                 // 0..63
    const int bm   = (tile >> 4) * BM2;        // 4 row tiles
    const int bn   = (tile & 15) * BN2;        // 16 col tiles
    const int tid  = threadIdx.x;
    const int lane = tid & 63;
    const int wv   = tid >> 6;                 // 8 waves, 2x4
    const int wr   = (wv >> 2) * 64;
    const int wc   = (wv & 3) * 64;
    const int fr   = lane & 15;
    const int ke   = (lane >> 4) * 8;

    f32x4 acc[4][4];
#pragma unroll
    for (int m = 0; m < 4; ++m)
#pragma unroll
        for (int n = 0; n < 4; ++n) acc[m][n] = (f32x4){0.f, 0.f, 0.f, 0.f};

    const int tr = tid >> 2;                   // 0..127
    const int tc = (tid & 3) << 4;             // 0,16,32,48

    for (int kt = 0; kt < 1024 / BK2; ++kt) {
        const int k0 = ks * 1024 + kt * BK2;
        float4 ra[4], rb[2][4];
        {
            const float4* ga = (const float4*)(X + (size_t)(bm + tr) * DIM + k0 + tc);
#pragma unroll
            for (int q = 0; q < 4; ++q) ra[q] = ga[q];
#pragma unroll
            for (int h = 0; h < 2; ++h) {
                const float4* gw = (const float4*)(W + (size_t)(bn + h * 128 + tr) * DIM + k0 + tc);
#pragma unroll
                for (int q = 0; q < 4; ++q) rb[h][q] = gw[q];
            }
        }
        __syncthreads();
        *(short8*)&As[tr * LDT + tc]     = pack8(ra[0], ra[1]);
        *(short8*)&As[tr * LDT + tc + 8] = pack8(ra[2], ra[3]);
#pragma unroll
        for (int h = 0; h < 2; ++h) {
            *(short8*)&Bs[(h * 128 + tr) * LDT + tc]     = pack8(rb[h][0], rb[h][1]);
            *(short8*)&Bs[(h * 128 + tr) * LDT + tc + 8] = pack8(rb[h][2], rb[h][3]);
        }
        __syncthreads();
#pragma unroll
        for (int kk = 0; kk < BK2; kk += 32) {
            short8 af[4], bf[4];
#pragma unroll
            for (int m = 0; m < 4; ++m)
                af[m] = *(const short8*)&As[(wr + m * 16 + fr) * LDT + kk + ke];
#pragma unroll
            for (int n = 0; n < 4; ++n)
                bf[n] = *(const short8*)&Bs[(wc + n * 16 + fr) * LDT + kk + ke];
#pragma unroll
            for (int m = 0; m < 4; ++m)
#pragma unroll
                for (int n = 0; n < 4; ++n)
                    acc[m][n] = __builtin_amdgcn_mfma_f32_16x16x32_bf16(
                        __builtin_bit_cast(bf16x8, af[m]),
                        __builtin_bit_cast(bf16x8, bf[n]),
                        acc[m][n], 0, 0, 0);
        }
    }
    float* dst = (ks == 0) ? out : (parts + (size_t)(ks - 1) * ROWS * DIM);
#pragma unroll
    for (int n = 0; n < 4; ++n) {
        const int col = bn + wc + n * 16 + fr;
        const float bv = (ks == 0) ? bias[col] : 0.f;
#pragma unroll
        for (int m = 0; m < 4; ++m) {
            const int rbase = bm + wr + m * 16 + (lane >> 4) * 4;
#pragma unroll
            for (int r = 0; r < 4; ++r)
                dst[(size_t)(rbase + r) * DIM + col] = acc[m][n][r] + bv;
        }
    }
}

// ---------------------------------------------------------------------------
// 2b) fallback GEMM (R3 version): BM=64 BN=128, full K, 256 thr
// ---------------------------------------------------------------------------
__global__ __launch_bounds__(256) void kgemm_small(const float* __restrict__ X, const float* __restrict__ W,
                                                   const float* __restrict__ bias, float* __restrict__ out) {
    __shared__ short As[64 * LDT];
    __shared__ short Bs[128 * LDT];
    const int tid  = threadIdx.x;
    const int bn   = (blockIdx.x & 31) * 128;
    const int bm   = (blockIdx.x >> 5) * 64;
    const int lane = tid & 63;
    const int wv   = tid >> 6;
    const int wr   = (wv >> 1) * 32;
    const int wc   = (wv & 1) * 64;
    const int fr   = lane & 15;
    const int ke   = (lane >> 4) * 8;

    f32x4 acc[2][4];
#pragma unroll
    for (int m = 0; m < 2; ++m)
#pragma unroll
        for (int n = 0; n < 4; ++n) acc[m][n] = (f32x4){0.f, 0.f, 0.f, 0.f};

    const int tr = tid >> 2;
    const int tc = (tid & 3) << 4;

    for (int kt = 0; kt < DIM / 64; ++kt) {
        const int k0 = kt * 64;
        float4 ra[4], rb[2][4];
        {
            const float4* ga = (const float4*)(X + (size_t)(bm + tr) * DIM + k0 + tc);
#pragma unroll
            for (int q = 0; q < 4; ++q) ra[q] = ga[q];
#pragma unroll
            for (int h = 0; h < 2; ++h) {
                const float4* gw = (const float4*)(W + (size_t)(bn + h * 64 + tr) * DIM + k0 + tc);
#pragma unroll
                for (int q = 0; q < 4; ++q) rb[h][q] = gw[q];
            }
        }
        __syncthreads();
        *(short8*)&As[tr * LDT + tc]     = pack8(ra[0], ra[1]);
        *(short8*)&As[tr * LDT + tc + 8] = pack8(ra[2], ra[3]);
#pragma unroll
        for (int h = 0; h < 2; ++h) {
            *(short8*)&Bs[(h * 64 + tr) * LDT + tc]     = pack8(rb[h][0], rb[h][1]);
            *(short8*)&Bs[(h * 64 + tr) * LDT + tc + 8] = pack8(rb[h][2], rb[h][3]);
        }
        __syncthreads();
#pragma unroll
        for (int kk = 0; kk < 64; kk += 32) {
            short8 af[2], bf[4];
#pragma unroll
            for (int m = 0; m < 2; ++m)
                af[m] = *(const short8*)&As[(wr + m * 16 + fr) * LDT + kk + ke];
#pragma unroll
            for (int n = 0; n < 4; ++n)
                bf[n] = *(const short8*)&Bs[(wc + n * 16 + fr) * LDT + kk + ke];
#pragma unroll
            for (int m = 0; m < 2; ++m)
#pragma unroll
                for (int n = 0; n < 4; ++n)
                    acc[m][n] = __builtin_amdgcn_mfma_f32_16x16x32_bf16(
                        __builtin_bit_cast(bf16x8, af[m]),
                        __builtin_bit_cast(bf16x8, bf[n]),
                        acc[m][n], 0, 0, 0);
        }
    }
#pragma unroll
    for (int n = 0; n < 4; ++n) {
        const int col = bn + wc + n * 16 + fr;
        const float bv = bias[col];
#pragma unroll
        for (int m = 0; m < 2; ++m) {
            const int rbase = bm + wr + m * 16 + (lane >> 4) * 4;
#pragma unroll
            for (int r = 0; r < 4; ++r)
                out[(size_t)(rbase + r) * DIM + col] = acc[m][n][r] + bv;
        }
    }
}

// ---------------------------------------------------------------------------
// 3) walk kernel: 1 wave / 2 rows, 3-stage pipeline; adds split-K partials
// ---------------------------------------------------------------------------
__global__ __launch_bounds__(64) void kwalk(const float* __restrict__ X, const float* __restrict__ vec,
                                            const uint4* __restrict__ recs, const int* __restrict__ cnts,
                                            const float* __restrict__ parts, int nparts,
                                            float* __restrict__ out) {
    __shared__ float2 rw[DIM + 2];
    const int pr   = blockIdx.x;
    const int lane = threadIdx.x;
    const int rA   = pr * 2, rB = pr * 2 + 1;

    {
        const float4* xa = (const float4*)(X + (size_t)rA * DIM);
        const float4* xb = (const float4*)(X + (size_t)rB * DIM);
        for (int c4 = lane; c4 < DIM / 4; c4 += 64) {
            const float4 a = xa[c4], b = xb[c4];
            rw[c4 * 4 + 0] = make_float2(a.x, b.x);
            rw[c4 * 4 + 1] = make_float2(a.y, b.y);
            rw[c4 * 4 + 2] = make_float2(a.z, b.z);
            rw[c4 * 4 + 3] = make_float2(a.w, b.w);
        }
        if (lane < 2) rw[DIM + lane] = make_float2(0.f, 0.f);
    }

    const int cnreg = cnts[lane < NSLOT ? lane : 0];

    for (int slot = 0; slot < NSLOT; ++slot) {
        if (slot == NW2) {      // between walks: yp = vec * yp
            const float4* v4 = (const float4*)vec;
            for (int c4 = lane; c4 < DIM / 4; c4 += 64) {
                const float4 v = v4[c4];
#pragma unroll
                for (int q = 0; q < 4; ++q) {
                    float2 tv = rw[c4 * 4 + q];
                    const float sc = (q == 0) ? v.x : (q == 1) ? v.y : (q == 2) ? v.z : v.w;
                    tv.x *= sc; tv.y *= sc;
                    rw[c4 * 4 + q] = tv;
                }
            }
        }
        const int nit = __shfl(cnreg, slot) >> 7;
        const uint4* base = recs + (size_t)slot * SLOT;

        uint4 rd0A = base[2 * 128 + lane], rd0B = base[2 * 128 + 64 + lane];
        uint4 rd1A = base[3 * 128 + lane], rd1B = base[3 * 128 + 64 + lane];
        uint4 c0A  = base[lane],           c0B  = base[64 + lane];
        uint4 c1A  = base[128 + lane],     c1B  = base[192 + lane];

        int   i0a = c0A.x & 0xFFFF, j0a = (int)(c0A.x >> 16);
        int   i0b = c0B.x & 0xFFFF, j0b = (int)(c0B.x >> 16);
        float cc0a = bitf(c0A.y), ss0a = bitf(c0A.z);
        float cc0b = bitf(c0B.y), ss0b = bitf(c0B.z);
        float2 g0ai = rw[i0a], g0aj = rw[j0a], g0bi = rw[i0b], g0bj = rw[j0b];

        int   i1a = c1A.x & 0xFFFF, j1a = (int)(c1A.x >> 16);
        int   i1b = c1B.x & 0xFFFF, j1b = (int)(c1B.x >> 16);
        float cc1a = bitf(c1A.y), ss1a = bitf(c1A.z);
        float cc1b = bitf(c1B.y), ss1b = bitf(c1B.z);
        float2 g1ai = rw[i1a], g1aj = rw[j1a], g1bi = rw[i1b], g1bj = rw[j1b];

#pragma unroll 4
        for (int k = 0; k < nit; ++k) {
            const int kc = (k + 4 < nit) ? (k + 4) : (nit - 1);
            const uint4 mA = base[(size_t)kc * 128 + lane];
            const uint4 mB = base[(size_t)kc * 128 + 64 + lane];

            const int   i2a = rd0A.x & 0xFFFF, j2a = (int)(rd0A.x >> 16);
            const int   i2b = rd0B.x & 0xFFFF, j2b = (int)(rd0B.x >> 16);
            const float cc2a = bitf(rd0A.y), ss2a = bitf(rd0A.z);
            const float cc2b = bitf(rd0B.y), ss2b = bitf(rd0B.z);
            const float2 g2ai = rw[i2a], g2aj = rw[j2a];
            const float2 g2bi = rw[i2b], g2bj = rw[j2b];

            float2 wia, wja, wib, wjb;
            wia.x = fmaf(cc0a, g0ai.x,  ss0a * g0aj.x);
            wia.y = fmaf(cc0a, g0ai.y,  ss0a * g0aj.y);
            wja.x = fmaf(cc0a, g0aj.x, -ss0a * g0ai.x);
            wja.y = fmaf(cc0a, g0aj.y, -ss0a * g0ai.y);
            wib.x = fmaf(cc0b, g0bi.x,  ss0b * g0bj.x);
            wib.y = fmaf(cc0b, g0bi.y,  ss0b * g0bj.y);
            wjb.x = fmaf(cc0b, g0bj.x, -ss0b * g0bi.x);
            wjb.y = fmaf(cc0b, g0bj.y, -ss0b * g0bi.y);
            rw[i0a] = wia; rw[j0a] = wja; rw[i0b] = wib; rw[j0b] = wjb;

            i0a = i1a; j0a = j1a; cc0a = cc1a; ss0a = ss1a; g0ai = g1ai; g0aj = g1aj;
            i0b = i1b; j0b = j1b; cc0b = cc1b; ss0b = ss1b; g0bi = g1bi; g0bj = g1bj;
            i1a = i2a; j1a = j2a; cc1a = cc2a; ss1a = ss2a; g1ai = g2ai; g1aj = g2aj;
            i1b = i2b; j1b = j2b; cc1b = cc2b; ss1b = ss2b; g1bi = g2bi; g1bj = g2bj;
            rd0A = rd1A; rd0B = rd1B; rd1A = mA; rd1B = mB;
        }
    }

    float4* oa = (float4*)(out + (size_t)rA * DIM);
    float4* ob = (float4*)(out + (size_t)rB * DIM);
    const size_t PS = (size_t)ROWS * DIM / 4;
    const float4* qa = (const float4*)parts + (size_t)rA * (DIM / 4);
    const float4* qb = (const float4*)parts + (size_t)rB * (DIM / 4);
    for (int c4 = lane; c4 < DIM / 4; c4 += 64) {
        const float2 p0 = rw[c4 * 4 + 0], p1 = rw[c4 * 4 + 1];
        const float2 p2 = rw[c4 * 4 + 2], p3 = rw[c4 * 4 + 3];
        float4 ta = oa[c4], tb = ob[c4];
        if (nparts == 3) {
            const float4 a0 = qa[c4], a1 = qa[c4 + PS], a2 = qa[c4 + 2 * PS];
            const float4 b0 = qb[c4], b1 = qb[c4 + PS], b2 = qb[c4 + 2 * PS];
            ta.x += a0.x + a1.x + a2.x; ta.y += a0.y + a1.y + a2.y;
            ta.z += a0.z + a1.z + a2.z; ta.w += a0.w + a1.w + a2.w;
            tb.x += b0.x + b1.x + b2.x; tb.y += b0.y + b1.y + b2.y;
            tb.z += b0.z + b1.z + b2.z; tb.w += b0.w + b1.w + b2.w;
        }
        ta.x += p0.x; ta.y += p1.x; ta.z += p2.x; ta.w += p3.x;
        tb.x += p0.y; tb.y += p1.y; tb.z += p2.y; tb.w += p3.y;
        oa[c4] = ta; ob[c4] = tb;
    }
}

// ---------------------------------------------------------------------------
extern "C" void kernel_launch(void* const* d_in, const int* in_sizes, int n_in,
                              void* d_out, int out_size, void* d_ws, size_t ws_size,
                              hipStream_t stream) {
    const float* X    = (const float*)d_in[0];
    const float* W    = (const float*)d_in[1];
    const float* bias = (const float*)d_in[2];
    const float* vec  = (const float*)d_in[3];
    const int*   i1   = (const int*)d_in[4];
    const int*   j1   = (const int*)d_in[5];
    const float* c1   = (const float*)d_in[6];
    const float* s1   = (const float*)d_in[7];
    const int*   i2   = (const int*)d_in[8];
    const int*   j2   = (const int*)d_in[9];
    const float* c2   = (const float*)d_in[10];
    const float* s2   = (const float*)d_in[11];
    float* out = (float*)d_out;

    const size_t recs_bytes = (size_t)NSLOT * SLOT * 16;          // 6.29 MiB
    const size_t part_off   = (recs_bytes + 4096 + 255) & ~(size_t)255;
    const size_t part_bytes = 3ull * ROWS * DIM * 4;              // 24 MiB
    uint4* recs  = (uint4*)d_ws;
    int*   cnts  = (int*)((char*)d_ws + recs_bytes);
    float* parts = (float*)((char*)d_ws + part_off);
    const bool split = (ws_size >= part_off + part_bytes);

    hipLaunchKernelGGL(ksched, dim3(NSLOT), dim3(KT), 0, stream,
                       i1, j1, c1, s1, i2, j2, c2, s2, recs, cnts);
    if (split)
        hipLaunchKernelGGL(kgemm_big, dim3(256), dim3(512), 0, stream, X, W, bias, out, parts);
    else
        hipLaunchKernelGGL(kgemm_small, dim3(256), dim3(256), 0, stream, X, W, bias, out);
    hipLaunchKernelGGL(kwalk, dim3(ROWS / 2), dim3(64), 0, stream,
                       X, vec, recs, cnts, parts, split ? 3 : 0, out);
}